// Round 1
// baseline (80.954 us; speedup 1.0000x reference)
//
#include <hip/hip_runtime.h>

// IrregularMaxPool2d — mask is static ((i+j)%4 block pattern), all gather
// indices derived in closed form.
//
// Layout (per channel, fp32):
//   in : [g_hi 393216][g_cur 32768]                        stride 425984
//   out: [g_hi 393216][dont 16384][lo 4096]                stride 413696
//
// g_cur structure: coarse grid 256x256, row a has 128 cur elems (64 c's, 2 b's
// each). Group g (of 32) in row a = 4 consecutive g_cur floats =
//   [dont0, dont1, lo0, lo1]   if (a//2)%4 != 3
//   [lo0,  lo1,  dont0, dont1] if (a//2)%4 == 3
// Pool cell (u,v=(u+v)%4==3) taps rows 2u and 2u+1 at identical offsets.
//   dont out index: m = a*64 + 2g + {0,1}
//   lo   out index: t = u*32 + g

namespace {
constexpr int kC     = 128;
constexpr int kNIn   = 425984;
constexpr int kNOut  = 413696;
constexpr int kStart = 393216;
constexpr int kNDont = 16384;

__global__ void copy_hi(const float* __restrict__ in, float* __restrict__ out) {
    const int c  = blockIdx.y;
    const int n4 = blockIdx.x * blockDim.x + threadIdx.x;  // float4 index, [0, 98304)
    const float4 v = *reinterpret_cast<const float4*>(in + (size_t)c * kNIn + (size_t)n4 * 4);
    *reinterpret_cast<float4*>(out + (size_t)c * kNOut + (size_t)n4 * 4) = v;
}

__global__ void tail(const float* __restrict__ in, float* __restrict__ out) {
    const int c = blockIdx.y;
    const int t = blockIdx.x * blockDim.x + threadIdx.x;   // [0, 4096) = u*32 + g
    const int u = t >> 5;
    const int g = t & 31;

    const float* gc = in + (size_t)c * kNIn + kStart + 256 * u + 4 * g;
    const float4 r0 = *reinterpret_cast<const float4*>(gc);        // row 2u
    const float4 r1 = *reinterpret_cast<const float4*>(gc + 128);  // row 2u+1

    float* ob = out + (size_t)c * kNOut + kStart;
    float2 d0, d1;
    float lo;
    if ((u & 3) == 3) {   // value-3 (lo) pair comes first in the group
        d0 = make_float2(r0.z, r0.w);
        d1 = make_float2(r1.z, r1.w);
        lo = fmaxf(fmaxf(r0.x, r0.y), fmaxf(r1.x, r1.y));
    } else {              // dont pair first
        d0 = make_float2(r0.x, r0.y);
        d1 = make_float2(r1.x, r1.y);
        lo = fmaxf(fmaxf(r0.z, r0.w), fmaxf(r1.z, r1.w));
    }
    *reinterpret_cast<float2*>(ob + 128 * u + 2 * g)      = d0;  // dont, row 2u
    *reinterpret_cast<float2*>(ob + 128 * u + 64 + 2 * g) = d1;  // dont, row 2u+1
    ob[kNDont + 32 * u + g] = lo;                                // lo
}
}  // namespace

extern "C" void kernel_launch(void* const* d_in, const int* in_sizes, int n_in,
                              void* d_out, int out_size, void* d_ws, size_t ws_size,
                              hipStream_t stream) {
    const float* in = (const float*)d_in[0];
    float* out = (float*)d_out;
    copy_hi<<<dim3(kStart / 4 / 256, kC), 256, 0, stream>>>(in, out);
    tail<<<dim3(4096 / 256, kC), 256, 0, stream>>>(in, out);
}

// Round 3
// 66.985 us; speedup vs baseline: 1.2085x; 1.2085x over previous
//
#include <hip/hip_runtime.h>

// IrregularMaxPool2d — mask is static ((i+j)%4 block pattern), all gather
// indices derived in closed form.
//
// Layout (per channel, fp32):
//   in : [g_hi 393216][g_cur 32768]                        stride 425984
//   out: [g_hi 393216][dont 16384][lo 4096]                stride 413696
//
// g_cur structure: coarse grid 256x256, row a has 128 cur elems. Group g
// (of 32) in row a = 4 consecutive g_cur floats =
//   [dont0, dont1, lo0, lo1]   if (a//2)%4 != 3
//   [lo0,  lo1,  dont0, dont1] if (a//2)%4 == 3
// Pool cell (u, v: (u+v)%4==3) taps rows 2u and 2u+1 at identical offsets.
//
// Fused single kernel: per channel 4096 threads; each does 24 strided float4
// copies (4096*24 = 98304 = kStart/4) + exactly one tail item. Output stores
// are non-temporal (nt, evict-first) so the 218 MB input can stay
// Infinity-Cache-resident across graph replays while the 212 MB output
// streams to HBM.

namespace {
typedef float f32x4 __attribute__((ext_vector_type(4)));
typedef float f32x2 __attribute__((ext_vector_type(2)));

constexpr int kC     = 128;
constexpr int kNIn   = 425984;
constexpr int kNOut  = 413696;
constexpr int kStart = 393216;
constexpr int kNDont = 16384;
constexpr int kTPC   = 4096;               // threads per channel
constexpr int kIters = kStart / 4 / kTPC;  // 24 float4 copies per thread

__global__ __launch_bounds__(256) void fused(const float* __restrict__ in,
                                             float* __restrict__ out) {
    const int c = blockIdx.y;
    const int t = blockIdx.x * blockDim.x + threadIdx.x;  // [0, 4096)
    const float* inc = in + (size_t)c * kNIn;
    float* outc = out + (size_t)c * kNOut;

    // ---- tail loads first (long-latency, overlap with copy loop) ----
    const int u = t >> 5;
    const int g = t & 31;
    const float* gc = inc + kStart + 256 * u + 4 * g;
    const f32x4 r0 = *reinterpret_cast<const f32x4*>(gc);        // row 2u
    const f32x4 r1 = *reinterpret_cast<const f32x4*>(gc + 128);  // row 2u+1

    // ---- bulk passthrough copy, NT stores ----
#pragma unroll 8
    for (int k = 0; k < kIters; ++k) {
        const int n4 = t + k * kTPC;
        const f32x4 v = *reinterpret_cast<const f32x4*>(inc + (size_t)n4 * 4);
        __builtin_nontemporal_store(v, reinterpret_cast<f32x4*>(outc + (size_t)n4 * 4));
    }

    // ---- tail compute + stores ----
    f32x2 d0, d1;
    float lo;
    if ((u & 3) == 3) {   // value-3 (lo) pair comes first in the group
        d0 = f32x2{r0.z, r0.w};
        d1 = f32x2{r1.z, r1.w};
        lo = fmaxf(fmaxf(r0.x, r0.y), fmaxf(r1.x, r1.y));
    } else {              // dont pair first
        d0 = f32x2{r0.x, r0.y};
        d1 = f32x2{r1.x, r1.y};
        lo = fmaxf(fmaxf(r0.z, r0.w), fmaxf(r1.z, r1.w));
    }
    float* ob = outc + kStart;
    __builtin_nontemporal_store(d0, reinterpret_cast<f32x2*>(ob + 128 * u + 2 * g));
    __builtin_nontemporal_store(d1, reinterpret_cast<f32x2*>(ob + 128 * u + 64 + 2 * g));
    __builtin_nontemporal_store(lo, ob + kNDont + 32 * u + g);
}
}  // namespace

extern "C" void kernel_launch(void* const* d_in, const int* in_sizes, int n_in,
                              void* d_out, int out_size, void* d_ws, size_t ws_size,
                              hipStream_t stream) {
    const float* in = (const float*)d_in[0];
    float* out = (float*)d_out;
    fused<<<dim3(kTPC / 256, kC), 256, 0, stream>>>(in, out);
}